// Round 11
// baseline (588.670 us; speedup 1.0000x reference)
//
#include <hip/hip_runtime.h>
#include <hip/hip_bf16.h>
#include <stdint.h>

#define NN 8192   // nodes == OUT
#define KIN 512   // input features

typedef __attribute__((ext_vector_type(8))) short bfx8;   // 8 bf16 (4 VGPRs) MFMA operand
typedef __attribute__((ext_vector_type(4))) float f32x4;  // MFMA accumulator
typedef __attribute__((ext_vector_type(4))) short sh4;

__device__ __forceinline__ float b2f(unsigned short u) {
  union { unsigned int i; float f; } z; z.i = ((unsigned int)u) << 16; return z.f;
}
__device__ __forceinline__ unsigned short f2b(float f) {
  __hip_bfloat16 h = __float2bfloat16(f);
  union { __hip_bfloat16 h; unsigned short u; } z; z.h = h; return z.u;
}

// async global->LDS, 16B per lane. LDS dest: wave-uniform base + lane*16.
__device__ __forceinline__ void async16(void* lds, const void* g) {
  __builtin_amdgcn_global_load_lds(
      (const __attribute__((address_space(1))) unsigned int*)g,
      (__attribute__((address_space(3))) unsigned int*)lds,
      16, 0, 0);
}

// fp32 -> bf16 convert (RNE), 4 elems/thread
__global__ __launch_bounds__(256)
void cvt_f32_bf16(const float* __restrict__ in, unsigned short* __restrict__ out, int n4) {
  int i = blockIdx.x * 256 + threadIdx.x;
  if (i >= n4) return;
  const float4 v = reinterpret_cast<const float4*>(in)[i];
  sh4 o;
  o.x = (short)f2b(v.x); o.y = (short)f2b(v.y);
  o.z = (short)f2b(v.z); o.w = (short)f2b(v.w);
  reinterpret_cast<sh4*>(out)[i] = o;
}

// sum 8 bf16 partial planes (fp32 accum) -> bf16. n8 = elems/8.
__global__ __launch_bounds__(256)
void reduce_cvt(const unsigned short* __restrict__ P, unsigned short* __restrict__ out, int n8) {
  const int i = blockIdx.x * 256 + threadIdx.x;
  if (i >= n8) return;
  const size_t plane = (size_t)NN * KIN / 8;   // in bfx8 units
  const bfx8* P8 = reinterpret_cast<const bfx8*>(P);
  bfx8 v = P8[i];
  float s[8];
#pragma unroll
  for (int j = 0; j < 8; ++j) s[j] = b2f((unsigned short)v[j]);
#pragma unroll
  for (int sp = 1; sp < 8; ++sp) {
    const bfx8 w = P8[i + sp * plane];
#pragma unroll
    for (int j = 0; j < 8; ++j) s[j] += b2f((unsigned short)w[j]);
  }
  bfx8 o;
#pragma unroll
  for (int j = 0; j < 8; ++j) o[j] = (short)f2b(s[j]);
  reinterpret_cast<bfx8*>(out)[i] = o;
}

// x (NR x NC f32) -> xT (NC x NR bf16)  AND  xb (NR x NC bf16)  (single x read)
__global__ __launch_bounds__(256)
void transpose_cvt(const float* __restrict__ x, unsigned short* __restrict__ xT,
                   unsigned short* __restrict__ xb, int NR, int NC) {
  __shared__ float t[64][65];
  const int i0 = blockIdx.x << 6;  // row block in x
  const int c0 = blockIdx.y << 6;  // col block in x
  const int tid = threadIdx.x;
  const int rl = tid >> 4;          // 0..15
  const int cl = (tid & 15) << 2;   // 0..60 step 4
#pragma unroll
  for (int ps = 0; ps < 4; ++ps) {
    const int r = rl + (ps << 4);
    const float4 v = *reinterpret_cast<const float4*>(&x[(size_t)(i0 + r) * NC + c0 + cl]);
    t[r][cl] = v.x; t[r][cl + 1] = v.y; t[r][cl + 2] = v.z; t[r][cl + 3] = v.w;
    sh4 o;
    o.x = (short)f2b(v.x); o.y = (short)f2b(v.y);
    o.z = (short)f2b(v.z); o.w = (short)f2b(v.w);
    *reinterpret_cast<sh4*>(&xb[(size_t)(i0 + r) * NC + c0 + cl]) = o;
  }
  __syncthreads();
  const int cr = tid >> 3;          // 0..31
  const int il = (tid & 7) << 3;    // 0..56 step 8
#pragma unroll
  for (int ps = 0; ps < 2; ++ps) {
    const int c = cr + (ps << 5);
    bfx8 o;
#pragma unroll
    for (int j = 0; j < 8; ++j) o[j] = (short)f2b(t[il + j][c]);
    *reinterpret_cast<bfx8*>(&xT[(size_t)(c0 + c) * NR + i0 + il]) = o;
  }
}

// ============================================================================
// 256x256-tile NT GEMM for the K=512 shapes. BK=32, 8 waves (2x4; each wave
// owns 128x64), same proven 2-barrier double-buffer loop as gemm_bt, 64KiB LDS.
// 4x fewer blocks and 2x more MFMA per barrier-pair than the 128^2 kernel ->
// amortizes the per-iter vmcnt(0)+barrier stall that dominates at K=512.
// Grid 1024 = 32x32 tiles; XCD chunk (128) -> 4x8 supertile (A 1MiB + B 2MiB
// working set fits 4MiB per-XCD L2). MODE 0: fp32*rowscale NT; MODE 1: bf16 NT.
// ============================================================================
template<int MODE>
__global__ __launch_bounds__(512, 1)
void gemm256b(const unsigned short* __restrict__ A,
              const unsigned short* __restrict__ B,
              void* __restrict__ C,
              const float* __restrict__ rowscale,
              int M, int Nc, int K)
{
  __shared__ unsigned short As[2][256 * 32];
  __shared__ unsigned short Bs[2][256 * 32];

  const int tid  = threadIdx.x;   // 0..511
  const int lane = tid & 63;
  const int wid  = tid >> 6;      // 0..7
  const int wm   = wid >> 2;      // 0..1 row half (128 rows)
  const int wn   = wid & 3;       // 0..3 col quarter (64 cols)

  // XCD swizzle + bijective 2D supertile map (grid 1024 = 32x32 tiles)
  const int cpx = gridDim.x >> 3;                     // 128 blocks per XCD
  const int swz = (blockIdx.x & 7) * cpx + (blockIdx.x >> 3);
  const int x = swz >> 7;                             // XCD 0..7
  const int l = swz & 127;
  const int s = l >> 5;                               // n-supertile group 0..3
  const int w = l & 31;                               // 4x8 within supertile
  const int bm = ((x << 2) | (w >> 3)) << 8;          // 32 m-tiles
  const int bn = ((s << 3) | (w & 7)) << 8;           // 32 n-tiles

  // staging: issue ss in {0,1}: byte off = tid*16 + ss*8192 within 16KiB tile
  const int u0  = tid << 4;
  const int r0  = u0 >> 6;                            // 0..127
  const int k0e = (u0 & 63) >> 1;
  const unsigned short* Ag0 = A + (size_t)(bm + r0) * K + k0e;
  const unsigned short* Ag1 = A + (size_t)(bm + r0 + 128) * K + k0e;
  const unsigned short* Bg0 = B + (size_t)(bn + r0) * K + k0e;
  const unsigned short* Bg1 = B + (size_t)(bn + r0 + 128) * K + k0e;
  const int wbase = (wid << 10);                      // wave-uniform byte base

  f32x4 acc[8][4];
#pragma unroll
  for (int m = 0; m < 8; ++m)
#pragma unroll
    for (int n = 0; n < 4; ++n)
      acc[m][n] = (f32x4){0.f, 0.f, 0.f, 0.f};

  auto stage = [&](int buf, int kk) {
    char* la = (char*)&As[buf][0] + wbase;
    char* lb = (char*)&Bs[buf][0] + wbase;
    async16(la,        Ag0 + kk);
    async16(la + 8192, Ag1 + kk);
    async16(lb,        Bg0 + kk);
    async16(lb + 8192, Bg1 + kk);
  };

  stage(0, 0);
  __syncthreads();

  const int nk   = K >> 5;                  // 16
  const int arow = (wm << 7) + (lane & 15);
  const int brow = (wn << 6) + (lane & 15);
  const int koff = (lane >> 4) << 3;

  for (int kt = 0; kt < nk; ++kt) {
    const int cur = kt & 1;
    if (kt + 1 < nk) stage(cur ^ 1, (kt + 1) << 5);

    bfx8 af[8], bf[4];
#pragma unroll
    for (int m = 0; m < 8; ++m)
      af[m] = *reinterpret_cast<const bfx8*>(&As[cur][(arow + (m << 4)) * 32 + koff]);
#pragma unroll
    for (int n = 0; n < 4; ++n)
      bf[n] = *reinterpret_cast<const bfx8*>(&Bs[cur][(brow + (n << 4)) * 32 + koff]);

#pragma unroll
    for (int m = 0; m < 8; ++m)
#pragma unroll
      for (int n = 0; n < 4; ++n)
        acc[m][n] = __builtin_amdgcn_mfma_f32_16x16x32_bf16(af[m], bf[n], acc[m][n], 0, 0, 0);

    __syncthreads();  // drains vmcnt (next buffer staged) + guards buffer reuse
  }

  // C/D layout: col = lane&15, row = (lane>>4)*4 + reg
  const int l15 = lane & 15;
  const int rq  = (lane >> 4) << 2;
#pragma unroll
  for (int m = 0; m < 8; ++m) {
    const int rowb = bm + (wm << 7) + (m << 4) + rq;
#pragma unroll
    for (int j = 0; j < 4; ++j) {
      const int r = rowb + j;
      if (MODE == 1) {
        unsigned short* Cb = (unsigned short*)C;
#pragma unroll
        for (int n = 0; n < 4; ++n)
          __builtin_nontemporal_store(f2b(acc[m][n][j]),
              &Cb[(size_t)r * Nc + bn + (wn << 6) + (n << 4) + l15]);
      } else {
        const float sc = rowscale[r];
        float* Cf = (float*)C;
#pragma unroll
        for (int n = 0; n < 4; ++n)
          __builtin_nontemporal_store(acc[m][n][j] * sc,
              &Cf[(size_t)r * Nc + bn + (wn << 6) + (n << 4) + l15]);
      }
    }
  }
}

// NT GEMM: C[M x Nc] = A[M x K] * B[Nc x K]^T   (both row-major, K contiguous)
// 128x128 tile, BK=32, 4 waves (2x2 of 64x64), 16x16x32 bf16 MFMA.
// MODE 2: C bf16 partial plane at C + split*M*Nc (split-K; temporal stores).
template<int MODE, int SPLITS>
__global__ __launch_bounds__(256)
void gemm_bt(const unsigned short* __restrict__ A,
             const unsigned short* __restrict__ B,
             void* __restrict__ C,
             const float* __restrict__ rowscale,
             int M, int Nc, int K)
{
  __shared__ unsigned short As[2][128 * 32];
  __shared__ unsigned short Bs[2][128 * 32];

  const int tid  = threadIdx.x;
  const int lane = tid & 63;
  const int wave = tid >> 6;
  const int wr   = wave >> 1, wc = wave & 1;

  const int nwg = gridDim.x;
  const int cpx = nwg >> 3;
  const int bid = blockIdx.x;
  const int swz = (bid & 7) * cpx + (bid >> 3);
  const int bps = nwg / SPLITS;     // blocks per split
  const int split = swz / bps;
  const int rem   = swz % bps;
  const int nbn = Nc >> 7;
  const int bm  = (rem / nbn) << 7;
  const int bn  = (rem % nbn) << 7;
  const int klen  = K / SPLITS;
  const int kbase = split * klen;

  const int off0 = (wave << 10) + (lane << 4);
  const int r0   = off0 >> 6;
  const int k0e  = (off0 & 63) >> 1;
  const int r1   = r0 + 64;

  const unsigned short* Ag0 = A + (size_t)(bm + r0) * K + kbase + k0e;
  const unsigned short* Ag1 = A + (size_t)(bm + r1) * K + kbase + k0e;
  const unsigned short* Bg0 = B + (size_t)(bn + r0) * K + kbase + k0e;
  const unsigned short* Bg1 = B + (size_t)(bn + r1) * K + kbase + k0e;

  f32x4 acc[4][4];
#pragma unroll
  for (int m = 0; m < 4; ++m)
#pragma unroll
    for (int n = 0; n < 4; ++n)
      acc[m][n] = (f32x4){0.f, 0.f, 0.f, 0.f};

  const int ldsoff = (wave << 10);

  auto stage = [&](int buf, int kk) {
    char* la = (char*)&As[buf][0] + ldsoff;
    char* lb = (char*)&Bs[buf][0] + ldsoff;
    async16(la,        Ag0 + kk);
    async16(la + 4096, Ag1 + kk);
    async16(lb,        Bg0 + kk);
    async16(lb + 4096, Bg1 + kk);
  };

  stage(0, 0);
  __syncthreads();

  const int nk   = klen >> 5;
  const int arow = (wr << 6) + (lane & 15);
  const int brow = (wc << 6) + (lane & 15);
  const int koff = (lane >> 4) << 3;

  for (int kt = 0; kt < nk; ++kt) {
    const int cur = kt & 1;
    if (kt + 1 < nk) stage(cur ^ 1, (kt + 1) << 5);

    bfx8 af[4], bf[4];
#pragma unroll
    for (int m = 0; m < 4; ++m)
      af[m] = *reinterpret_cast<const bfx8*>(&As[cur][(arow + (m << 4)) * 32 + koff]);
#pragma unroll
    for (int n = 0; n < 4; ++n)
      bf[n] = *reinterpret_cast<const bfx8*>(&Bs[cur][(brow + (n << 4)) * 32 + koff]);

#pragma unroll
    for (int m = 0; m < 4; ++m)
#pragma unroll
      for (int n = 0; n < 4; ++n)
        acc[m][n] = __builtin_amdgcn_mfma_f32_16x16x32_bf16(af[m], bf[n], acc[m][n], 0, 0, 0);

    __syncthreads();  // drains vmcnt: next buffer staged; also guards buffer reuse
  }

  // C/D layout: col = lane&15, row = (lane>>4)*4 + reg
#pragma unroll
  for (int m = 0; m < 4; ++m) {
    const int rowb = bm + (wr << 6) + (m << 4) + ((lane >> 4) << 2);
#pragma unroll
    for (int j = 0; j < 4; ++j) {
      const int r = rowb + j;
      unsigned short* Cb = (unsigned short*)C + (size_t)split * M * Nc;
#pragma unroll
      for (int n = 0; n < 4; ++n)
        Cb[(size_t)r * Nc + bn + (wc << 6) + (n << 4) + (lane & 15)] = f2b(acc[m][n][j]);
    }
  }
}

// row-wise reduce over bf16 matrix. MODE 0: 1/sqrt(sum x^2)  MODE 1: 1/sum
template<int MODE>
__global__ __launch_bounds__(256)
void row_reduce(const unsigned short* __restrict__ X, float* __restrict__ out, int ncols) {
  const int row = blockIdx.x;
  const unsigned short* xr = X + (size_t)row * ncols;
  float s = 0.f;
  for (int c = threadIdx.x * 8; c < ncols; c += 2048) {
    bfx8 v = *reinterpret_cast<const bfx8*>(xr + c);
#pragma unroll
    for (int j = 0; j < 8; ++j) {
      float f = b2f((unsigned short)v[j]);
      s += (MODE == 0) ? f * f : f;
    }
  }
#pragma unroll
  for (int o = 32; o > 0; o >>= 1) s += __shfl_down(s, o);
  __shared__ float red[4];
  if ((threadIdx.x & 63) == 0) red[threadIdx.x >> 6] = s;
  __syncthreads();
  if (threadIdx.x == 0) {
    float t = red[0] + red[1] + red[2] + red[3];
    out[row] = (MODE == 0) ? (1.0f / sqrtf(t)) : (1.0f / t);
  }
}

// in-place 1/x over a small float vector
__global__ __launch_bounds__(256)
void invert_vec(float* __restrict__ v) {
  const int i = blockIdx.x * 256 + threadIdx.x;
  v[i] = 1.0f / v[i];
}

// p[i,j] = adj[i,j] ? exp(lrelu(hT[j,i]*a1[i]*icn[j] + hT[i,j]*a2[j]*icn[i])) : 0
// Vectorized: 8 j per thread. Also accumulates row sums of p into rs_raw[i].
__global__ __launch_bounds__(256)
void scores_kernel(const unsigned short* __restrict__ hT,
                   const int* __restrict__ adj,
                   const float* __restrict__ a,
                   const float* __restrict__ icn,
                   unsigned short* __restrict__ p,
                   float* __restrict__ rs_raw,
                   int strip)
{
  __shared__ unsigned short T1t[64][72];

  const int tid   = threadIdx.x;
  const int i0    = blockIdx.x << 6;
  const int jbase = blockIdx.y * strip;
  const int ntile = strip >> 6;

  const int slot = tid & 7;
  const int jb   = slot << 3;
  const int il0  = tid >> 3;
  const int i_p0 = i0 + il0;
  const int i_p1 = i_p0 + 32;
  const float a1_0 = a[i_p0], ici_0 = icn[i_p0];
  const float a1_1 = a[i_p1], ici_1 = icn[i_p1];
  float rs0 = 0.f, rs1 = 0.f;

  const int rblk0 = (((jb >> 3) ^ ((il0 >> 3) & 7)) << 3);
  const int rblk1 = (((jb >> 3) ^ (((il0 + 32) >> 3) & 7)) << 3);

  for (int jt = 0; jt < ntile; ++jt) {
    const int j0 = jbase + (jt << 6);
    __syncthreads();
#pragma unroll
    for (int ss = 0; ss < 2; ++ss) {
      const int u  = tid + (ss << 8);
      const int jr = u >> 3;
      const int cb = (u & 7) << 3;
      const bfx8 v = *reinterpret_cast<const bfx8*>(hT + (size_t)(j0 + jr) * NN + i0 + cb);
      const int colp = ((((jr >> 3) ^ (u & 7)) << 3) | (jr & 7));
#pragma unroll
      for (int k = 0; k < 8; ++k) T1t[cb + k][colp] = (unsigned short)v[k];
    }
    __syncthreads();

    const int j = j0 + jb;
    const float4 ic0 = *reinterpret_cast<const float4*>(icn + j);
    const float4 ic1 = *reinterpret_cast<const float4*>(icn + j + 4);
    const float4 a20 = *reinterpret_cast<const float4*>(a + NN + j);
    const float4 a21 = *reinterpret_cast<const float4*>(a + NN + j + 4);
    const float icj[8] = {ic0.x, ic0.y, ic0.z, ic0.w, ic1.x, ic1.y, ic1.z, ic1.w};
    const float a2j[8] = {a20.x, a20.y, a20.z, a20.w, a21.x, a21.y, a21.z, a21.w};

#pragma unroll
    for (int ps = 0; ps < 2; ++ps) {
      const int il   = (ps == 0) ? il0 : il0 + 32;
      const int i    = (ps == 0) ? i_p0 : i_p1;
      const float a1 = (ps == 0) ? a1_0 : a1_1;
      const float ii = (ps == 0) ? ici_0 : ici_1;
      const int rb   = (ps == 0) ? rblk0 : rblk1;

      const bfx8 hijv = *reinterpret_cast<const bfx8*>(&T1t[il][rb]);
      const bfx8 hjiv = *reinterpret_cast<const bfx8*>(hT + (size_t)i * NN + j);
      const int4 ad0  = *reinterpret_cast<const int4*>(adj + (size_t)i * NN + j);
      const int4 ad1  = *reinterpret_cast<const int4*>(adj + (size_t)i * NN + j + 4);
      const int adv[8] = {ad0.x, ad0.y, ad0.z, ad0.w, ad1.x, ad1.y, ad1.z, ad1.w};

      bfx8 o;
      float rs = 0.f;
#pragma unroll
      for (int k = 0; k < 8; ++k) {
        const float hij = b2f((unsigned short)hijv[k]);
        const float hji = b2f((unsigned short)hjiv[k]);
        const float e0  = hij * (a1 * icj[k]) + hji * (a2j[k] * ii);
        const float e   = e0 > 0.f ? e0 : 0.2f * e0;
        const float pv  = (adv[k] > 0) ? __expf(e) : 0.f;
        const unsigned short ub = f2b(pv);
        o[k] = (short)ub;
        rs += b2f(ub);   // accumulate the rounded value (matches reading back bf16 p)
      }
      *reinterpret_cast<bfx8*>(p + (size_t)i * NN + j) = o;
      if (ps == 0) rs0 += rs; else rs1 += rs;
    }
  }

  // reduce across the 8 j-slot lanes (lane groups are 8-aligned)
#pragma unroll
  for (int o = 1; o < 8; o <<= 1) {
    rs0 += __shfl_xor(rs0, o);
    rs1 += __shfl_xor(rs1, o);
  }
  if (slot == 0) {
    atomicAdd(rs_raw + i_p0, rs0);
    atomicAdd(rs_raw + i_p1, rs1);
  }
}

extern "C" void kernel_launch(void* const* d_in, const int* in_sizes, int n_in,
                              void* d_out, int out_size, void* d_ws, size_t ws_size,
                              hipStream_t stream)
{
  (void)in_sizes; (void)n_in; (void)out_size; (void)ws_size;
  const float* x   = (const float*)d_in[0];
  const int*   adj = (const int*)d_in[1];
  const float* W   = (const float*)d_in[2];
  const float* a   = (const float*)d_in[3];
  float* out = (float*)d_out;

  char* ws = (char*)d_ws;
  // layout (no recycling; ~288 MiB used, ws ~1 GiB per poison fill):
  //   hT 128MiB | p 128MiB | icn 32KiB | irs 32KiB | xb 8MiB | Wb 8MiB | xT 8MiB | Axb 8MiB
  // split-K bf16 partials (8 x 8MiB) live in d_out, dead before gemm2b writes it.
  unsigned short* hT = (unsigned short*)ws;
  unsigned short* p  = (unsigned short*)(ws + 134217728ull);
  float* icn = (float*)(ws + 268435456ull);
  float* irs = (float*)(ws + 268435456ull + 32768ull);
  unsigned short* xb  = (unsigned short*)(ws + 268435456ull + 65536ull);
  unsigned short* Wb  = xb + (size_t)NN * KIN;
  unsigned short* xT  = Wb + (size_t)NN * KIN;
  unsigned short* Axb = xT + (size_t)NN * KIN;
  unsigned short* parts = (unsigned short*)out;   // 64MiB bf16, overwritten later

  // irs doubles as the raw row-sum accumulator for scores' atomics
  hipMemsetAsync(irs, 0, NN * sizeof(float), stream);

  const int n4 = NN * KIN / 4;
  // xb + xT from a single read of x
  transpose_cvt<<<dim3(NN / 64, KIN / 64), 256, 0, stream>>>(x, xT, xb, NN, KIN);
  cvt_f32_bf16<<<n4 / 256, 256, 0, stream>>>(W, Wb, n4);

  // hT[j,i] = sum_k W[j,k] x[i,k]  (NT: A=W rows j, B=x rows i), 256^2 tiles
  gemm256b<1><<<1024, 512, 0, stream>>>(Wb, xb, hT, nullptr, NN, NN, KIN);

  // icn[j] = 1 / ||hT[j,:]|| = 1 / col_norm(h)[j]
  row_reduce<0><<<NN, 256, 0, stream>>>(hT, icn, NN);

  // p[i,j] = adj ? exp(lrelu(...)) : 0 ; rowsums -> irs (raw)
  scores_kernel<<<dim3(128, 16), 256, 0, stream>>>(hT, adj, a, icn, p, irs, NN / 16);

  // irs[i] = 1 / rowsum[i]
  invert_vec<<<NN / 256, 256, 0, stream>>>(irs);

  // Ax[i,c] = sum_j p[i,j] * x[j,c]  (split-K 8, bf16 partials in d_out)
  gemm_bt<2, 8><<<2048, 256, 0, stream>>>(p, xT, parts, nullptr, NN, KIN, NN);

  // Axb = bf16(sum of 8 bf16 partial planes)
  reduce_cvt<<<NN * KIN / 8 / 256, 256, 0, stream>>>(parts, Axb, NN * KIN / 8);

  // out[i,j] = (sum_c Ax[i,c] * W[j,c]) * irs[i]  (K=512), 256^2 tiles
  gemm256b<0><<<1024, 512, 0, stream>>>(Axb, Wb, out, irs, NN, NN, KIN);
}

// Round 12
// 500.264 us; speedup vs baseline: 1.1767x; 1.1767x over previous
//
#include <hip/hip_runtime.h>
#include <hip/hip_bf16.h>
#include <stdint.h>

#define NN 8192   // nodes == OUT
#define KIN 512   // input features

typedef __attribute__((ext_vector_type(8))) short bfx8;   // 8 bf16 (4 VGPRs) MFMA operand
typedef __attribute__((ext_vector_type(4))) float f32x4;  // MFMA accumulator
typedef __attribute__((ext_vector_type(4))) short sh4;

__device__ __forceinline__ float b2f(unsigned short u) {
  union { unsigned int i; float f; } z; z.i = ((unsigned int)u) << 16; return z.f;
}
__device__ __forceinline__ unsigned short f2b(float f) {
  __hip_bfloat16 h = __float2bfloat16(f);
  union { __hip_bfloat16 h; unsigned short u; } z; z.h = h; return z.u;
}

// async global->LDS, 16B per lane. LDS dest: wave-uniform base + lane*16.
__device__ __forceinline__ void async16(void* lds, const void* g) {
  __builtin_amdgcn_global_load_lds(
      (const __attribute__((address_space(1))) unsigned int*)g,
      (__attribute__((address_space(3))) unsigned int*)lds,
      16, 0, 0);
}

// sum 8 bf16 partial planes (fp32 accum) -> bf16. n8 = elems/8.
__global__ __launch_bounds__(256)
void reduce_cvt(const unsigned short* __restrict__ P, unsigned short* __restrict__ out, int n8) {
  const int i = blockIdx.x * 256 + threadIdx.x;
  if (i >= n8) return;
  const size_t plane = (size_t)NN * KIN / 8;   // in bfx8 units
  const bfx8* P8 = reinterpret_cast<const bfx8*>(P);
  bfx8 v = P8[i];
  float s[8];
#pragma unroll
  for (int j = 0; j < 8; ++j) s[j] = b2f((unsigned short)v[j]);
#pragma unroll
  for (int sp = 1; sp < 8; ++sp) {
    const bfx8 w = P8[i + sp * plane];
#pragma unroll
    for (int j = 0; j < 8; ++j) s[j] += b2f((unsigned short)w[j]);
  }
  bfx8 o;
#pragma unroll
  for (int j = 0; j < 8; ++j) o[j] = (short)f2b(s[j]);
  reinterpret_cast<bfx8*>(out)[i] = o;
}

// x (NR x NC f32) -> xT (NC x NR bf16) AND xb (NR x NC bf16) (single x read);
// additionally converts W (NR*NC floats) -> Wb bf16 (grid covers it exactly).
__global__ __launch_bounds__(256)
void transpose_cvt(const float* __restrict__ x, unsigned short* __restrict__ xT,
                   unsigned short* __restrict__ xb,
                   const float* __restrict__ W, unsigned short* __restrict__ Wb,
                   int NR, int NC) {
  __shared__ float t[64][65];
  const int i0 = blockIdx.x << 6;  // row block in x
  const int c0 = blockIdx.y << 6;  // col block in x
  const int tid = threadIdx.x;
  const int rl = tid >> 4;          // 0..15
  const int cl = (tid & 15) << 2;   // 0..60 step 4
#pragma unroll
  for (int ps = 0; ps < 4; ++ps) {
    const int r = rl + (ps << 4);
    const float4 v = *reinterpret_cast<const float4*>(&x[(size_t)(i0 + r) * NC + c0 + cl]);
    t[r][cl] = v.x; t[r][cl + 1] = v.y; t[r][cl + 2] = v.z; t[r][cl + 3] = v.w;
    sh4 o;
    o.x = (short)f2b(v.x); o.y = (short)f2b(v.y);
    o.z = (short)f2b(v.z); o.w = (short)f2b(v.w);
    *reinterpret_cast<sh4*>(&xb[(size_t)(i0 + r) * NC + c0 + cl]) = o;
  }
  __syncthreads();
  const int cr = tid >> 3;          // 0..31
  const int il = (tid & 7) << 3;    // 0..56 step 8
#pragma unroll
  for (int ps = 0; ps < 2; ++ps) {
    const int c = cr + (ps << 5);
    bfx8 o;
#pragma unroll
    for (int j = 0; j < 8; ++j) o[j] = (short)f2b(t[il + j][c]);
    *reinterpret_cast<bfx8*>(&xT[(size_t)(c0 + c) * NR + i0 + il]) = o;
  }
  // W convert: 1024 blocks x 256 threads x 4 float4 = NR*NC floats exactly
  const int nblk = gridDim.x * gridDim.y;            // 1024
  const int bidf = blockIdx.y * gridDim.x + blockIdx.x;
  const int nthr = nblk << 8;                        // 262144
  const int base = (bidf << 8) + tid;
  const float4* W4 = reinterpret_cast<const float4*>(W);
#pragma unroll
  for (int k = 0; k < 4; ++k) {
    const int idx = base + k * nthr;
    const float4 v = W4[idx];
    sh4 o;
    o.x = (short)f2b(v.x); o.y = (short)f2b(v.y);
    o.z = (short)f2b(v.z); o.w = (short)f2b(v.w);
    reinterpret_cast<sh4*>(Wb)[idx] = o;
  }
}

// NT GEMM: C[M x Nc] = A[M x K] * B[Nc x K]^T   (both row-major, K contiguous)
// 128x128 tile, BK=32, 4 waves (2x2 of 64x64), 16x16x32 bf16 MFMA.
// MODE 0: C fp32, scaled by 1/rowsum[row] (raw sums in aux), nontemporal.
// MODE 1: C bf16, nontemporal (hT: re-read only by later kernels).
// MODE 2: C bf16 partial plane at C + split*M*Nc (split-K; temporal stores).
// L2T: 2D super-tile mapping per XCD chunk so each XCD's concurrent blocks
//      work on an 8x8 tile region (A-slice 1MiB + B-slice 1MiB fits 4MiB L2).
//      Requires SPLITS==1, M==Nc, nwg==4096 (chunk 512, 64x64 tile grid).
template<int MODE, int SPLITS, int L2T>
__global__ __launch_bounds__(256)
void gemm_bt(const unsigned short* __restrict__ A,
             const unsigned short* __restrict__ B,
             void* __restrict__ C,
             const float* __restrict__ aux,
             int M, int Nc, int K)
{
  __shared__ unsigned short As[2][128 * 32];
  __shared__ unsigned short Bs[2][128 * 32];

  const int tid  = threadIdx.x;
  const int lane = tid & 63;
  const int wave = tid >> 6;
  const int wr   = wave >> 1, wc = wave & 1;

  // XCD-aware bijective swizzle (gridDim.x % 8 == 0 in all uses here)
  const int nwg = gridDim.x;
  const int cpx = nwg >> 3;
  const int bid = blockIdx.x;
  const int swz = (bid & 7) * cpx + (bid >> 3);

  int split, bm, bn;
  if (L2T) {
    // bijective: (x, l) <-> (bm_idx, bn_idx); x = XCD chunk (512 blocks)
    split = 0;
    const int x = swz >> 9;
    const int l = swz & 511;
    const int s = l >> 6;        // super-tile column group
    const int w = l & 63;        // 8x8 within super-tile
    bm = (((x << 3) | (w >> 3))) << 7;
    bn = (((s << 3) | (w & 7))) << 7;
  } else {
    const int bps = nwg / SPLITS;     // blocks per split
    split = swz / bps;
    const int rem = swz % bps;
    const int nbn = Nc >> 7;
    bm = (rem / nbn) << 7;
    bn = (rem % nbn) << 7;
  }
  const int klen  = K / SPLITS;
  const int kbase = split * klen;

  const int off0 = (wave << 10) + (lane << 4);
  const int r0   = off0 >> 6;
  const int k0e  = (off0 & 63) >> 1;
  const int r1   = r0 + 64;

  const unsigned short* Ag0 = A + (size_t)(bm + r0) * K + kbase + k0e;
  const unsigned short* Ag1 = A + (size_t)(bm + r1) * K + kbase + k0e;
  const unsigned short* Bg0 = B + (size_t)(bn + r0) * K + kbase + k0e;
  const unsigned short* Bg1 = B + (size_t)(bn + r1) * K + kbase + k0e;

  f32x4 acc[4][4];
#pragma unroll
  for (int m = 0; m < 4; ++m)
#pragma unroll
    for (int n = 0; n < 4; ++n)
      acc[m][n] = (f32x4){0.f, 0.f, 0.f, 0.f};

  const int ldsoff = (wave << 10);

  auto stage = [&](int buf, int kk) {
    char* la = (char*)&As[buf][0] + ldsoff;
    char* lb = (char*)&Bs[buf][0] + ldsoff;
    async16(la,        Ag0 + kk);
    async16(la + 4096, Ag1 + kk);
    async16(lb,        Bg0 + kk);
    async16(lb + 4096, Bg1 + kk);
  };

  stage(0, 0);
  __syncthreads();

  const int nk   = klen >> 5;
  const int arow = (wr << 6) + (lane & 15);
  const int brow = (wc << 6) + (lane & 15);
  const int koff = (lane >> 4) << 3;

  for (int kt = 0; kt < nk; ++kt) {
    const int cur = kt & 1;
    if (kt + 1 < nk) stage(cur ^ 1, (kt + 1) << 5);

    bfx8 af[4], bf[4];
#pragma unroll
    for (int m = 0; m < 4; ++m)
      af[m] = *reinterpret_cast<const bfx8*>(&As[cur][(arow + (m << 4)) * 32 + koff]);
#pragma unroll
    for (int n = 0; n < 4; ++n)
      bf[n] = *reinterpret_cast<const bfx8*>(&Bs[cur][(brow + (n << 4)) * 32 + koff]);

#pragma unroll
    for (int m = 0; m < 4; ++m)
#pragma unroll
      for (int n = 0; n < 4; ++n)
        acc[m][n] = __builtin_amdgcn_mfma_f32_16x16x32_bf16(af[m], bf[n], acc[m][n], 0, 0, 0);

    __syncthreads();  // drains vmcnt: next buffer staged; also guards buffer reuse
  }

  // C/D layout: col = lane&15, row = (lane>>4)*4 + reg
#pragma unroll
  for (int m = 0; m < 4; ++m) {
    const int rowb = bm + (wr << 6) + (m << 4) + ((lane >> 4) << 2);
#pragma unroll
    for (int j = 0; j < 4; ++j) {
      const int r = rowb + j;
      if (MODE == 1) {
        unsigned short* Cb = (unsigned short*)C;
#pragma unroll
        for (int n = 0; n < 4; ++n)
          __builtin_nontemporal_store(f2b(acc[m][n][j]),
              &Cb[(size_t)r * Nc + bn + (wc << 6) + (n << 4) + (lane & 15)]);
      } else if (MODE == 0) {
        const float s = 1.0f / aux[r];   // aux holds raw rowsums (IEEE divide,
        float* Cf = (float*)C;           // identical to the old invert_vec pass)
#pragma unroll
        for (int n = 0; n < 4; ++n)
          __builtin_nontemporal_store(acc[m][n][j] * s,
              &Cf[(size_t)r * Nc + bn + (wc << 6) + (n << 4) + (lane & 15)]);
      } else {
        unsigned short* Cb = (unsigned short*)C + (size_t)split * M * Nc;
#pragma unroll
        for (int n = 0; n < 4; ++n)
          Cb[(size_t)r * Nc + bn + (wc << 6) + (n << 4) + (lane & 15)] = f2b(acc[m][n][j]);
      }
    }
  }
}

// row-wise reduce over bf16 matrix. MODE 0: 1/sqrt(sum x^2)  MODE 1: 1/sum
template<int MODE>
__global__ __launch_bounds__(256)
void row_reduce(const unsigned short* __restrict__ X, float* __restrict__ out, int ncols) {
  const int row = blockIdx.x;
  const unsigned short* xr = X + (size_t)row * ncols;
  float s = 0.f;
  for (int c = threadIdx.x * 8; c < ncols; c += 2048) {
    bfx8 v = *reinterpret_cast<const bfx8*>(xr + c);
#pragma unroll
    for (int j = 0; j < 8; ++j) {
      float f = b2f((unsigned short)v[j]);
      s += (MODE == 0) ? f * f : f;
    }
  }
#pragma unroll
  for (int o = 32; o > 0; o >>= 1) s += __shfl_down(s, o);
  __shared__ float red[4];
  if ((threadIdx.x & 63) == 0) red[threadIdx.x >> 6] = s;
  __syncthreads();
  if (threadIdx.x == 0) {
    float t = red[0] + red[1] + red[2] + red[3];
    out[row] = (MODE == 0) ? (1.0f / sqrtf(t)) : (1.0f / t);
  }
}

// p[i,j] = adj[i,j] ? exp(lrelu(hT[j,i]*a1[i]*icn[j] + hT[i,j]*a2[j]*icn[i])) : 0
// Vectorized: 8 j per thread. Also accumulates row sums of p into rs_raw[i].
__global__ __launch_bounds__(256)
void scores_kernel(const unsigned short* __restrict__ hT,
                   const int* __restrict__ adj,
                   const float* __restrict__ a,
                   const float* __restrict__ icn,
                   unsigned short* __restrict__ p,
                   float* __restrict__ rs_raw,
                   int strip)
{
  __shared__ unsigned short T1t[64][72];

  const int tid   = threadIdx.x;
  const int i0    = blockIdx.x << 6;
  const int jbase = blockIdx.y * strip;
  const int ntile = strip >> 6;

  const int slot = tid & 7;
  const int jb   = slot << 3;
  const int il0  = tid >> 3;
  const int i_p0 = i0 + il0;
  const int i_p1 = i_p0 + 32;
  const float a1_0 = a[i_p0], ici_0 = icn[i_p0];
  const float a1_1 = a[i_p1], ici_1 = icn[i_p1];
  float rs0 = 0.f, rs1 = 0.f;

  const int rblk0 = (((jb >> 3) ^ ((il0 >> 3) & 7)) << 3);
  const int rblk1 = (((jb >> 3) ^ (((il0 + 32) >> 3) & 7)) << 3);

  for (int jt = 0; jt < ntile; ++jt) {
    const int j0 = jbase + (jt << 6);
    __syncthreads();
#pragma unroll
    for (int ss = 0; ss < 2; ++ss) {
      const int u  = tid + (ss << 8);
      const int jr = u >> 3;
      const int cb = (u & 7) << 3;
      const bfx8 v = *reinterpret_cast<const bfx8*>(hT + (size_t)(j0 + jr) * NN + i0 + cb);
      const int colp = ((((jr >> 3) ^ (u & 7)) << 3) | (jr & 7));
#pragma unroll
      for (int k = 0; k < 8; ++k) T1t[cb + k][colp] = (unsigned short)v[k];
    }
    __syncthreads();

    const int j = j0 + jb;
    const float4 ic0 = *reinterpret_cast<const float4*>(icn + j);
    const float4 ic1 = *reinterpret_cast<const float4*>(icn + j + 4);
    const float4 a20 = *reinterpret_cast<const float4*>(a + NN + j);
    const float4 a21 = *reinterpret_cast<const float4*>(a + NN + j + 4);
    const float icj[8] = {ic0.x, ic0.y, ic0.z, ic0.w, ic1.x, ic1.y, ic1.z, ic1.w};
    const float a2j[8] = {a20.x, a20.y, a20.z, a20.w, a21.x, a21.y, a21.z, a21.w};

#pragma unroll
    for (int ps = 0; ps < 2; ++ps) {
      const int il   = (ps == 0) ? il0 : il0 + 32;
      const int i    = (ps == 0) ? i_p0 : i_p1;
      const float a1 = (ps == 0) ? a1_0 : a1_1;
      const float ii = (ps == 0) ? ici_0 : ici_1;
      const int rb   = (ps == 0) ? rblk0 : rblk1;

      const bfx8 hijv = *reinterpret_cast<const bfx8*>(&T1t[il][rb]);
      const bfx8 hjiv = *reinterpret_cast<const bfx8*>(hT + (size_t)i * NN + j);
      const int4 ad0  = *reinterpret_cast<const int4*>(adj + (size_t)i * NN + j);
      const int4 ad1  = *reinterpret_cast<const int4*>(adj + (size_t)i * NN + j + 4);
      const int adv[8] = {ad0.x, ad0.y, ad0.z, ad0.w, ad1.x, ad1.y, ad1.z, ad1.w};

      bfx8 o;
      float rs = 0.f;
#pragma unroll
      for (int k = 0; k < 8; ++k) {
        const float hij = b2f((unsigned short)hijv[k]);
        const float hji = b2f((unsigned short)hjiv[k]);
        const float e0  = hij * (a1 * icj[k]) + hji * (a2j[k] * ii);
        const float e   = e0 > 0.f ? e0 : 0.2f * e0;
        const float pv  = (adv[k] > 0) ? __expf(e) : 0.f;
        const unsigned short ub = f2b(pv);
        o[k] = (short)ub;
        rs += b2f(ub);   // accumulate the rounded value (matches reading back bf16 p)
      }
      *reinterpret_cast<bfx8*>(p + (size_t)i * NN + j) = o;
      if (ps == 0) rs0 += rs; else rs1 += rs;
    }
  }

  // reduce across the 8 j-slot lanes (lane groups are 8-aligned)
#pragma unroll
  for (int o = 1; o < 8; o <<= 1) {
    rs0 += __shfl_xor(rs0, o);
    rs1 += __shfl_xor(rs1, o);
  }
  if (slot == 0) {
    atomicAdd(rs_raw + i_p0, rs0);
    atomicAdd(rs_raw + i_p1, rs1);
  }
}

extern "C" void kernel_launch(void* const* d_in, const int* in_sizes, int n_in,
                              void* d_out, int out_size, void* d_ws, size_t ws_size,
                              hipStream_t stream)
{
  (void)in_sizes; (void)n_in; (void)out_size; (void)ws_size;
  const float* x   = (const float*)d_in[0];
  const int*   adj = (const int*)d_in[1];
  const float* W   = (const float*)d_in[2];
  const float* a   = (const float*)d_in[3];
  float* out = (float*)d_out;

  char* ws = (char*)d_ws;
  // layout (no recycling; ~288 MiB used, ws ~1 GiB per poison fill):
  //   hT 128MiB | p 128MiB | icn 32KiB | irs 32KiB | xb 8MiB | Wb 8MiB | xT 8MiB | Axb 8MiB
  // split-K bf16 partials (8 x 8MiB) live in d_out, dead before gemm2b writes it.
  unsigned short* hT = (unsigned short*)ws;
  unsigned short* p  = (unsigned short*)(ws + 134217728ull);
  float* icn = (float*)(ws + 268435456ull);
  float* irs = (float*)(ws + 268435456ull + 32768ull);
  unsigned short* xb  = (unsigned short*)(ws + 268435456ull + 65536ull);
  unsigned short* Wb  = xb + (size_t)NN * KIN;
  unsigned short* xT  = Wb + (size_t)NN * KIN;
  unsigned short* Axb = xT + (size_t)NN * KIN;
  unsigned short* parts = (unsigned short*)out;   // 64MiB bf16, overwritten later

  // irs doubles as the raw row-sum accumulator for scores' atomics
  hipMemsetAsync(irs, 0, NN * sizeof(float), stream);

  // xb + xT from a single read of x; W -> Wb in the same launch
  transpose_cvt<<<dim3(NN / 64, KIN / 64), 256, 0, stream>>>(x, xT, xb, W, Wb, NN, KIN);

  // hT[j,i] = sum_k W[j,k] x[i,k]  (NT: A=W rows j, B=x rows i)
  gemm_bt<1, 1, 1><<<4096, 256, 0, stream>>>(Wb, xb, hT, nullptr, NN, NN, KIN);

  // icn[j] = 1 / ||hT[j,:]|| = 1 / col_norm(h)[j]
  row_reduce<0><<<NN, 256, 0, stream>>>(hT, icn, NN);

  // p[i,j] = adj ? exp(lrelu(...)) : 0 ; raw rowsums -> irs
  scores_kernel<<<dim3(128, 16), 256, 0, stream>>>(hT, adj, a, icn, p, irs, NN / 16);

  // Ax[i,c] = sum_j p[i,j] * x[j,c]  (split-K 8, bf16 partials in d_out)
  gemm_bt<2, 8, 0><<<2048, 256, 0, stream>>>(p, xT, parts, nullptr, NN, KIN, NN);

  // Axb = bf16(sum of 8 bf16 partial planes)
  reduce_cvt<<<NN * KIN / 8 / 256, 256, 0, stream>>>(parts, Axb, NN * KIN / 8);

  // out[i,j] = (sum_c Ax[i,c] * W[j,c]) / rowsum[i]  (K=512; 1/x folded in)
  gemm_bt<0, 1, 1><<<4096, 256, 0, stream>>>(Axb, Wb, out, irs, NN, NN, KIN);
}

// Round 14
// 494.894 us; speedup vs baseline: 1.1895x; 1.0109x over previous
//
#include <hip/hip_runtime.h>
#include <hip/hip_bf16.h>
#include <stdint.h>

#define NN 8192   // nodes == OUT
#define KIN 512   // input features

typedef __attribute__((ext_vector_type(8))) short bfx8;   // 8 bf16 (4 VGPRs) MFMA operand
typedef __attribute__((ext_vector_type(4))) float f32x4;  // MFMA accumulator
typedef __attribute__((ext_vector_type(4))) short sh4;
typedef __attribute__((ext_vector_type(4))) int i32x4;    // clang vector (nontemporal-ok)

__device__ __forceinline__ float b2f(unsigned short u) {
  union { unsigned int i; float f; } z; z.i = ((unsigned int)u) << 16; return z.f;
}
__device__ __forceinline__ unsigned short f2b(float f) {
  __hip_bfloat16 h = __float2bfloat16(f);
  union { __hip_bfloat16 h; unsigned short u; } z; z.h = h; return z.u;
}

// async global->LDS, 16B per lane. LDS dest: wave-uniform base + lane*16.
__device__ __forceinline__ void async16(void* lds, const void* g) {
  __builtin_amdgcn_global_load_lds(
      (const __attribute__((address_space(1))) unsigned int*)g,
      (__attribute__((address_space(3))) unsigned int*)lds,
      16, 0, 0);
}

// sum 8 bf16 partial planes (fp32 accum) -> bf16. n8 = elems/8.
__global__ __launch_bounds__(256)
void reduce_cvt(const unsigned short* __restrict__ P, unsigned short* __restrict__ out, int n8) {
  const int i = blockIdx.x * 256 + threadIdx.x;
  if (i >= n8) return;
  const size_t plane = (size_t)NN * KIN / 8;   // in bfx8 units
  const bfx8* P8 = reinterpret_cast<const bfx8*>(P);
  bfx8 v = P8[i];
  float s[8];
#pragma unroll
  for (int j = 0; j < 8; ++j) s[j] = b2f((unsigned short)v[j]);
#pragma unroll
  for (int sp = 1; sp < 8; ++sp) {
    const bfx8 w = P8[i + sp * plane];
#pragma unroll
    for (int j = 0; j < 8; ++j) s[j] += b2f((unsigned short)w[j]);
  }
  bfx8 o;
#pragma unroll
  for (int j = 0; j < 8; ++j) o[j] = (short)f2b(s[j]);
  reinterpret_cast<bfx8*>(out)[i] = o;
}

// x (NR x NC f32) -> xT (NC x NR bf16) AND xb (NR x NC bf16) (single x read);
// additionally converts W (NR*NC floats) -> Wb bf16 (grid covers it exactly).
__global__ __launch_bounds__(256)
void transpose_cvt(const float* __restrict__ x, unsigned short* __restrict__ xT,
                   unsigned short* __restrict__ xb,
                   const float* __restrict__ W, unsigned short* __restrict__ Wb,
                   int NR, int NC) {
  __shared__ float t[64][65];
  const int i0 = blockIdx.x << 6;  // row block in x
  const int c0 = blockIdx.y << 6;  // col block in x
  const int tid = threadIdx.x;
  const int rl = tid >> 4;          // 0..15
  const int cl = (tid & 15) << 2;   // 0..60 step 4
#pragma unroll
  for (int ps = 0; ps < 4; ++ps) {
    const int r = rl + (ps << 4);
    const float4 v = *reinterpret_cast<const float4*>(&x[(size_t)(i0 + r) * NC + c0 + cl]);
    t[r][cl] = v.x; t[r][cl + 1] = v.y; t[r][cl + 2] = v.z; t[r][cl + 3] = v.w;
    sh4 o;
    o.x = (short)f2b(v.x); o.y = (short)f2b(v.y);
    o.z = (short)f2b(v.z); o.w = (short)f2b(v.w);
    *reinterpret_cast<sh4*>(&xb[(size_t)(i0 + r) * NC + c0 + cl]) = o;
  }
  __syncthreads();
  const int cr = tid >> 3;          // 0..31
  const int il = (tid & 7) << 3;    // 0..56 step 8
#pragma unroll
  for (int ps = 0; ps < 2; ++ps) {
    const int c = cr + (ps << 5);
    bfx8 o;
#pragma unroll
    for (int j = 0; j < 8; ++j) o[j] = (short)f2b(t[il + j][c]);
    *reinterpret_cast<bfx8*>(&xT[(size_t)(c0 + c) * NR + i0 + il]) = o;
  }
  // W convert: 1024 blocks x 256 threads x 4 float4 = NR*NC floats exactly
  const int nblk = gridDim.x * gridDim.y;            // 1024
  const int bidf = blockIdx.y * gridDim.x + blockIdx.x;
  const int nthr = nblk << 8;                        // 262144
  const int base = (bidf << 8) + tid;
  const float4* W4 = reinterpret_cast<const float4*>(W);
#pragma unroll
  for (int k = 0; k < 4; ++k) {
    const int idx = base + k * nthr;
    const float4 v = W4[idx];
    sh4 o;
    o.x = (short)f2b(v.x); o.y = (short)f2b(v.y);
    o.z = (short)f2b(v.z); o.w = (short)f2b(v.w);
    reinterpret_cast<sh4*>(Wb)[idx] = o;
  }
}

// NT GEMM: C[M x Nc] = A[M x K] * B[Nc x K]^T   (both row-major, K contiguous)
// 128x128 tile, BK=32, 4 waves (2x2 of 64x64), 16x16x32 bf16 MFMA.
// MODE 0: C fp32, scaled by 1/rowsum[row] (raw sums in aux), nontemporal.
// MODE 1: C bf16, nontemporal (hT: re-read only by later kernels).
// MODE 2: C bf16 partial plane at C + split*M*Nc (split-K; temporal stores).
// L2T: 2D super-tile mapping per XCD chunk so each XCD's concurrent blocks
//      work on an 8x8 tile region (A-slice 1MiB + B-slice 1MiB fits 4MiB L2).
//      Requires SPLITS==1, M==Nc, nwg==4096 (chunk 512, 64x64 tile grid).
template<int MODE, int SPLITS, int L2T>
__global__ __launch_bounds__(256)
void gemm_bt(const unsigned short* __restrict__ A,
             const unsigned short* __restrict__ B,
             void* __restrict__ C,
             const float* __restrict__ aux,
             int M, int Nc, int K)
{
  __shared__ unsigned short As[2][128 * 32];
  __shared__ unsigned short Bs[2][128 * 32];

  const int tid  = threadIdx.x;
  const int lane = tid & 63;
  const int wave = tid >> 6;
  const int wr   = wave >> 1, wc = wave & 1;

  // XCD-aware bijective swizzle (gridDim.x % 8 == 0 in all uses here)
  const int nwg = gridDim.x;
  const int cpx = nwg >> 3;
  const int bid = blockIdx.x;
  const int swz = (bid & 7) * cpx + (bid >> 3);

  int split, bm, bn;
  if (L2T) {
    // bijective: (x, l) <-> (bm_idx, bn_idx); x = XCD chunk (512 blocks)
    split = 0;
    const int x = swz >> 9;
    const int l = swz & 511;
    const int s = l >> 6;        // super-tile column group
    const int w = l & 63;        // 8x8 within super-tile
    bm = (((x << 3) | (w >> 3))) << 7;
    bn = (((s << 3) | (w & 7))) << 7;
  } else {
    const int bps = nwg / SPLITS;     // blocks per split
    split = swz / bps;
    const int rem = swz % bps;
    const int nbn = Nc >> 7;
    bm = (rem / nbn) << 7;
    bn = (rem % nbn) << 7;
  }
  const int klen  = K / SPLITS;
  const int kbase = split * klen;

  const int off0 = (wave << 10) + (lane << 4);
  const int r0   = off0 >> 6;
  const int k0e  = (off0 & 63) >> 1;
  const int r1   = r0 + 64;

  const unsigned short* Ag0 = A + (size_t)(bm + r0) * K + kbase + k0e;
  const unsigned short* Ag1 = A + (size_t)(bm + r1) * K + kbase + k0e;
  const unsigned short* Bg0 = B + (size_t)(bn + r0) * K + kbase + k0e;
  const unsigned short* Bg1 = B + (size_t)(bn + r1) * K + kbase + k0e;

  f32x4 acc[4][4];
#pragma unroll
  for (int m = 0; m < 4; ++m)
#pragma unroll
    for (int n = 0; n < 4; ++n)
      acc[m][n] = (f32x4){0.f, 0.f, 0.f, 0.f};

  const int ldsoff = (wave << 10);

  auto stage = [&](int buf, int kk) {
    char* la = (char*)&As[buf][0] + ldsoff;
    char* lb = (char*)&Bs[buf][0] + ldsoff;
    async16(la,        Ag0 + kk);
    async16(la + 4096, Ag1 + kk);
    async16(lb,        Bg0 + kk);
    async16(lb + 4096, Bg1 + kk);
  };

  stage(0, 0);
  __syncthreads();

  const int nk   = klen >> 5;
  const int arow = (wr << 6) + (lane & 15);
  const int brow = (wc << 6) + (lane & 15);
  const int koff = (lane >> 4) << 3;

  for (int kt = 0; kt < nk; ++kt) {
    const int cur = kt & 1;
    if (kt + 1 < nk) stage(cur ^ 1, (kt + 1) << 5);

    bfx8 af[4], bf[4];
#pragma unroll
    for (int m = 0; m < 4; ++m)
      af[m] = *reinterpret_cast<const bfx8*>(&As[cur][(arow + (m << 4)) * 32 + koff]);
#pragma unroll
    for (int n = 0; n < 4; ++n)
      bf[n] = *reinterpret_cast<const bfx8*>(&Bs[cur][(brow + (n << 4)) * 32 + koff]);

#pragma unroll
    for (int m = 0; m < 4; ++m)
#pragma unroll
      for (int n = 0; n < 4; ++n)
        acc[m][n] = __builtin_amdgcn_mfma_f32_16x16x32_bf16(af[m], bf[n], acc[m][n], 0, 0, 0);

    __syncthreads();  // drains vmcnt: next buffer staged; also guards buffer reuse
  }

  // C/D layout: col = lane&15, row = (lane>>4)*4 + reg
#pragma unroll
  for (int m = 0; m < 4; ++m) {
    const int rowb = bm + (wr << 6) + (m << 4) + ((lane >> 4) << 2);
#pragma unroll
    for (int j = 0; j < 4; ++j) {
      const int r = rowb + j;
      if (MODE == 1) {
        unsigned short* Cb = (unsigned short*)C;
#pragma unroll
        for (int n = 0; n < 4; ++n)
          __builtin_nontemporal_store(f2b(acc[m][n][j]),
              &Cb[(size_t)r * Nc + bn + (wc << 6) + (n << 4) + (lane & 15)]);
      } else if (MODE == 0) {
        const float s = 1.0f / aux[r];   // raw rowsums; IEEE divide == old invert_vec
        float* Cf = (float*)C;
#pragma unroll
        for (int n = 0; n < 4; ++n)
          __builtin_nontemporal_store(acc[m][n][j] * s,
              &Cf[(size_t)r * Nc + bn + (wc << 6) + (n << 4) + (lane & 15)]);
      } else {
        unsigned short* Cb = (unsigned short*)C + (size_t)split * M * Nc;
#pragma unroll
        for (int n = 0; n < 4; ++n)
          Cb[(size_t)r * Nc + bn + (wc << 6) + (n << 4) + (lane & 15)] = f2b(acc[m][n][j]);
      }
    }
  }
}

// row-wise reduce over bf16 matrix. MODE 0: 1/sqrt(sum x^2)  MODE 1: 1/sum
template<int MODE>
__global__ __launch_bounds__(256)
void row_reduce(const unsigned short* __restrict__ X, float* __restrict__ out, int ncols) {
  const int row = blockIdx.x;
  const unsigned short* xr = X + (size_t)row * ncols;
  float s = 0.f;
  for (int c = threadIdx.x * 8; c < ncols; c += 2048) {
    bfx8 v = *reinterpret_cast<const bfx8*>(xr + c);
#pragma unroll
    for (int j = 0; j < 8; ++j) {
      float f = b2f((unsigned short)v[j]);
      s += (MODE == 0) ? f * f : f;
    }
  }
#pragma unroll
  for (int o = 32; o > 0; o >>= 1) s += __shfl_down(s, o);
  __shared__ float red[4];
  if ((threadIdx.x & 63) == 0) red[threadIdx.x >> 6] = s;
  __syncthreads();
  if (threadIdx.x == 0) {
    float t = red[0] + red[1] + red[2] + red[3];
    out[row] = (MODE == 0) ? (1.0f / sqrtf(t)) : (1.0f / t);
  }
}

// p[i,j] = adj[i,j] ? exp(lrelu(hT[j,i]*a1[i]*icn[j] + hT[i,j]*a2[j]*icn[i])) : 0
// Vectorized: 8 j per thread. Also accumulates row sums of p into rs_raw[i].
// adj is loaded NON-TEMPORAL (clang ext_vector i32x4): 256MiB read-once stream
// that would otherwise evict the L3-resident hT (reused 2x here).
__global__ __launch_bounds__(256)
void scores_kernel(const unsigned short* __restrict__ hT,
                   const int* __restrict__ adj,
                   const float* __restrict__ a,
                   const float* __restrict__ icn,
                   unsigned short* __restrict__ p,
                   float* __restrict__ rs_raw,
                   int strip)
{
  __shared__ unsigned short T1t[64][72];

  const int tid   = threadIdx.x;
  const int i0    = blockIdx.x << 6;
  const int jbase = blockIdx.y * strip;
  const int ntile = strip >> 6;

  const int slot = tid & 7;
  const int jb   = slot << 3;
  const int il0  = tid >> 3;
  const int i_p0 = i0 + il0;
  const int i_p1 = i_p0 + 32;
  const float a1_0 = a[i_p0], ici_0 = icn[i_p0];
  const float a1_1 = a[i_p1], ici_1 = icn[i_p1];
  float rs0 = 0.f, rs1 = 0.f;

  const int rblk0 = (((jb >> 3) ^ ((il0 >> 3) & 7)) << 3);
  const int rblk1 = (((jb >> 3) ^ (((il0 + 32) >> 3) & 7)) << 3);

  for (int jt = 0; jt < ntile; ++jt) {
    const int j0 = jbase + (jt << 6);
    __syncthreads();
#pragma unroll
    for (int ss = 0; ss < 2; ++ss) {
      const int u  = tid + (ss << 8);
      const int jr = u >> 3;
      const int cb = (u & 7) << 3;
      const bfx8 v = *reinterpret_cast<const bfx8*>(hT + (size_t)(j0 + jr) * NN + i0 + cb);
      const int colp = ((((jr >> 3) ^ (u & 7)) << 3) | (jr & 7));
#pragma unroll
      for (int k = 0; k < 8; ++k) T1t[cb + k][colp] = (unsigned short)v[k];
    }
    __syncthreads();

    const int j = j0 + jb;
    const float4 ic0 = *reinterpret_cast<const float4*>(icn + j);
    const float4 ic1 = *reinterpret_cast<const float4*>(icn + j + 4);
    const float4 a20 = *reinterpret_cast<const float4*>(a + NN + j);
    const float4 a21 = *reinterpret_cast<const float4*>(a + NN + j + 4);
    const float icj[8] = {ic0.x, ic0.y, ic0.z, ic0.w, ic1.x, ic1.y, ic1.z, ic1.w};
    const float a2j[8] = {a20.x, a20.y, a20.z, a20.w, a21.x, a21.y, a21.z, a21.w};

#pragma unroll
    for (int ps = 0; ps < 2; ++ps) {
      const int il   = (ps == 0) ? il0 : il0 + 32;
      const int i    = (ps == 0) ? i_p0 : i_p1;
      const float a1 = (ps == 0) ? a1_0 : a1_1;
      const float ii = (ps == 0) ? ici_0 : ici_1;
      const int rb   = (ps == 0) ? rblk0 : rblk1;

      const bfx8 hijv = *reinterpret_cast<const bfx8*>(&T1t[il][rb]);
      const bfx8 hjiv = *reinterpret_cast<const bfx8*>(hT + (size_t)i * NN + j);
      const i32x4 ad0 = __builtin_nontemporal_load(
          reinterpret_cast<const i32x4*>(adj + (size_t)i * NN + j));
      const i32x4 ad1 = __builtin_nontemporal_load(
          reinterpret_cast<const i32x4*>(adj + (size_t)i * NN + j + 4));
      const int adv[8] = {ad0.x, ad0.y, ad0.z, ad0.w, ad1.x, ad1.y, ad1.z, ad1.w};

      bfx8 o;
      float rs = 0.f;
#pragma unroll
      for (int k = 0; k < 8; ++k) {
        const float hij = b2f((unsigned short)hijv[k]);
        const float hji = b2f((unsigned short)hjiv[k]);
        const float e0  = hij * (a1 * icj[k]) + hji * (a2j[k] * ii);
        const float e   = e0 > 0.f ? e0 : 0.2f * e0;
        const float pv  = (adv[k] > 0) ? __expf(e) : 0.f;
        const unsigned short ub = f2b(pv);
        o[k] = (short)ub;
        rs += b2f(ub);   // accumulate the rounded value (matches reading back bf16 p)
      }
      *reinterpret_cast<bfx8*>(p + (size_t)i * NN + j) = o;
      if (ps == 0) rs0 += rs; else rs1 += rs;
    }
  }

  // reduce across the 8 j-slot lanes (lane groups are 8-aligned)
#pragma unroll
  for (int o = 1; o < 8; o <<= 1) {
    rs0 += __shfl_xor(rs0, o);
    rs1 += __shfl_xor(rs1, o);
  }
  if (slot == 0) {
    atomicAdd(rs_raw + i_p0, rs0);
    atomicAdd(rs_raw + i_p1, rs1);
  }
}

extern "C" void kernel_launch(void* const* d_in, const int* in_sizes, int n_in,
                              void* d_out, int out_size, void* d_ws, size_t ws_size,
                              hipStream_t stream)
{
  (void)in_sizes; (void)n_in; (void)out_size; (void)ws_size;
  const float* x   = (const float*)d_in[0];
  const int*   adj = (const int*)d_in[1];
  const float* W   = (const float*)d_in[2];
  const float* a   = (const float*)d_in[3];
  float* out = (float*)d_out;

  char* ws = (char*)d_ws;
  // layout (no recycling; ~288 MiB used, ws ~1 GiB per poison fill):
  //   hT 128MiB | p 128MiB | icn 32KiB | irs 32KiB | xb 8MiB | Wb 8MiB | xT 8MiB | Axb 8MiB
  // split-K bf16 partials (8 x 8MiB) live in d_out, dead before gemm2b writes it.
  unsigned short* hT = (unsigned short*)ws;
  unsigned short* p  = (unsigned short*)(ws + 134217728ull);
  float* icn = (float*)(ws + 268435456ull);
  float* irs = (float*)(ws + 268435456ull + 32768ull);
  unsigned short* xb  = (unsigned short*)(ws + 268435456ull + 65536ull);
  unsigned short* Wb  = xb + (size_t)NN * KIN;
  unsigned short* xT  = Wb + (size_t)NN * KIN;
  unsigned short* Axb = xT + (size_t)NN * KIN;
  unsigned short* parts = (unsigned short*)out;   // 64MiB bf16, overwritten later

  // irs doubles as the raw row-sum accumulator for scores' atomics
  hipMemsetAsync(irs, 0, NN * sizeof(float), stream);

  // xb + xT from a single read of x; W -> Wb in the same launch
  transpose_cvt<<<dim3(NN / 64, KIN / 64), 256, 0, stream>>>(x, xT, xb, W, Wb, NN, KIN);

  // hT[j,i] = sum_k W[j,k] x[i,k]  (NT: A=W rows j, B=x rows i)
  gemm_bt<1, 1, 1><<<4096, 256, 0, stream>>>(Wb, xb, hT, nullptr, NN, NN, KIN);

  // icn[j] = 1 / ||hT[j,:]|| = 1 / col_norm(h)[j]
  row_reduce<0><<<NN, 256, 0, stream>>>(hT, icn, NN);

  // p[i,j] = adj ? exp(lrelu(...)) : 0 ; raw rowsums -> irs. NT adj loads.
  scores_kernel<<<dim3(128, 32), 256, 0, stream>>>(hT, adj, a, icn, p, irs, NN / 32);

  // Ax[i,c] = sum_j p[i,j] * x[j,c]  (split-K 8, bf16 partials in d_out)
  gemm_bt<2, 8, 0><<<2048, 256, 0, stream>>>(p, xT, parts, nullptr, NN, KIN, NN);

  // Axb = bf16(sum of 8 bf16 partial planes)
  reduce_cvt<<<NN * KIN / 8 / 256, 256, 0, stream>>>(parts, Axb, NN * KIN / 8);

  // out[i,j] = (sum_c Ax[i,c] * W[j,c]) / rowsum[i]  (K=512; 1/x folded in)
  gemm_bt<0, 1, 1><<<4096, 256, 0, stream>>>(Axb, Wb, out, irs, NN, NN, KIN);
}

// Round 15
// 479.922 us; speedup vs baseline: 1.2266x; 1.0312x over previous
//
#include <hip/hip_runtime.h>
#include <hip/hip_bf16.h>
#include <stdint.h>

#define NN 8192   // nodes == OUT
#define KIN 512   // input features

typedef __attribute__((ext_vector_type(8))) short bfx8;   // 8 bf16 (4 VGPRs) MFMA operand
typedef __attribute__((ext_vector_type(4))) float f32x4;  // MFMA accumulator
typedef __attribute__((ext_vector_type(4))) short sh4;
typedef __attribute__((ext_vector_type(4))) int i32x4;    // clang vector (nontemporal-ok)

__device__ __forceinline__ float b2f(unsigned short u) {
  union { unsigned int i; float f; } z; z.i = ((unsigned int)u) << 16; return z.f;
}
__device__ __forceinline__ unsigned short f2b(float f) {
  __hip_bfloat16 h = __float2bfloat16(f);
  union { __hip_bfloat16 h; unsigned short u; } z; z.h = h; return z.u;
}

// async global->LDS, 16B per lane. LDS dest: wave-uniform base + lane*16.
__device__ __forceinline__ void async16(void* lds, const void* g) {
  __builtin_amdgcn_global_load_lds(
      (const __attribute__((address_space(1))) unsigned int*)g,
      (__attribute__((address_space(3))) unsigned int*)lds,
      16, 0, 0);
}

// sum 8 bf16 partial planes (fp32 accum) -> bf16. n8 = elems/8.
__global__ __launch_bounds__(256)
void reduce_cvt(const unsigned short* __restrict__ P, unsigned short* __restrict__ out, int n8) {
  const int i = blockIdx.x * 256 + threadIdx.x;
  if (i >= n8) return;
  const size_t plane = (size_t)NN * KIN / 8;   // in bfx8 units
  const bfx8* P8 = reinterpret_cast<const bfx8*>(P);
  bfx8 v = P8[i];
  float s[8];
#pragma unroll
  for (int j = 0; j < 8; ++j) s[j] = b2f((unsigned short)v[j]);
#pragma unroll
  for (int sp = 1; sp < 8; ++sp) {
    const bfx8 w = P8[i + sp * plane];
#pragma unroll
    for (int j = 0; j < 8; ++j) s[j] += b2f((unsigned short)w[j]);
  }
  bfx8 o;
#pragma unroll
  for (int j = 0; j < 8; ++j) o[j] = (short)f2b(s[j]);
  reinterpret_cast<bfx8*>(out)[i] = o;
}

// x (NR x NC f32) -> xT (NC x NR bf16) AND xb (NR x NC bf16) (single x read);
// additionally converts W (NR*NC floats) -> Wb bf16 (grid covers it exactly).
__global__ __launch_bounds__(256)
void transpose_cvt(const float* __restrict__ x, unsigned short* __restrict__ xT,
                   unsigned short* __restrict__ xb,
                   const float* __restrict__ W, unsigned short* __restrict__ Wb,
                   int NR, int NC) {
  __shared__ float t[64][65];
  const int i0 = blockIdx.x << 6;  // row block in x
  const int c0 = blockIdx.y << 6;  // col block in x
  const int tid = threadIdx.x;
  const int rl = tid >> 4;          // 0..15
  const int cl = (tid & 15) << 2;   // 0..60 step 4
#pragma unroll
  for (int ps = 0; ps < 4; ++ps) {
    const int r = rl + (ps << 4);
    const float4 v = *reinterpret_cast<const float4*>(&x[(size_t)(i0 + r) * NC + c0 + cl]);
    t[r][cl] = v.x; t[r][cl + 1] = v.y; t[r][cl + 2] = v.z; t[r][cl + 3] = v.w;
    sh4 o;
    o.x = (short)f2b(v.x); o.y = (short)f2b(v.y);
    o.z = (short)f2b(v.z); o.w = (short)f2b(v.w);
    *reinterpret_cast<sh4*>(&xb[(size_t)(i0 + r) * NC + c0 + cl]) = o;
  }
  __syncthreads();
  const int cr = tid >> 3;          // 0..31
  const int il = (tid & 7) << 3;    // 0..56 step 8
#pragma unroll
  for (int ps = 0; ps < 2; ++ps) {
    const int c = cr + (ps << 5);
    bfx8 o;
#pragma unroll
    for (int j = 0; j < 8; ++j) o[j] = (short)f2b(t[il + j][c]);
    *reinterpret_cast<bfx8*>(&xT[(size_t)(c0 + c) * NR + i0 + il]) = o;
  }
  // W convert: 1024 blocks x 256 threads x 4 float4 = NR*NC floats exactly
  const int nblk = gridDim.x * gridDim.y;            // 1024
  const int bidf = blockIdx.y * gridDim.x + blockIdx.x;
  const int nthr = nblk << 8;                        // 262144
  const int base = (bidf << 8) + tid;
  const float4* W4 = reinterpret_cast<const float4*>(W);
#pragma unroll
  for (int k = 0; k < 4; ++k) {
    const int idx = base + k * nthr;
    const float4 v = W4[idx];
    sh4 o;
    o.x = (short)f2b(v.x); o.y = (short)f2b(v.y);
    o.z = (short)f2b(v.z); o.w = (short)f2b(v.w);
    reinterpret_cast<sh4*>(Wb)[idx] = o;
  }
}

// v = 1 / sqrt(v) over a small float vector
__global__ __launch_bounds__(256)
void final_rsq(float* __restrict__ v) {
  const int i = blockIdx.x * 256 + threadIdx.x;
  v[i] = 1.0f / sqrtf(v[i]);
}

// NT GEMM: C[M x Nc] = A[M x K] * B[Nc x K]^T   (both row-major, K contiguous)
// 128x128 tile, BK=32, 4 waves (2x2 of 64x64), 16x16x32 bf16 MFMA.
// MODE 0: C fp32, scaled by 1/rowsum[row] (raw sums in aux), nontemporal.
// MODE 1: C bf16, nontemporal; if ICN, atomicAdd per-row sum(acc^2) into aux
//         (aux zeroed by launcher) -> fuses the col_norm reduction into gemm1.
// MODE 2: C bf16 partial plane at C + split*M*Nc (split-K; temporal stores).
// L2T: 2D super-tile mapping per XCD chunk so each XCD's concurrent blocks
//      work on an 8x8 tile region (A-slice 1MiB + B-slice 1MiB fits 4MiB L2).
//      Requires SPLITS==1, M==Nc, nwg==4096 (chunk 512, 64x64 tile grid).
template<int MODE, int SPLITS, int L2T, int ICN>
__global__ __launch_bounds__(256)
void gemm_bt(const unsigned short* __restrict__ A,
             const unsigned short* __restrict__ B,
             void* __restrict__ C,
             float* __restrict__ aux,
             int M, int Nc, int K)
{
  __shared__ unsigned short As[2][128 * 32];
  __shared__ unsigned short Bs[2][128 * 32];

  const int tid  = threadIdx.x;
  const int lane = tid & 63;
  const int wave = tid >> 6;
  const int wr   = wave >> 1, wc = wave & 1;

  // XCD-aware bijective swizzle (gridDim.x % 8 == 0 in all uses here)
  const int nwg = gridDim.x;
  const int cpx = nwg >> 3;
  const int bid = blockIdx.x;
  const int swz = (bid & 7) * cpx + (bid >> 3);

  int split, bm, bn;
  if (L2T) {
    // bijective: (x, l) <-> (bm_idx, bn_idx); x = XCD chunk (512 blocks)
    split = 0;
    const int x = swz >> 9;
    const int l = swz & 511;
    const int s = l >> 6;        // super-tile column group
    const int w = l & 63;        // 8x8 within super-tile
    bm = (((x << 3) | (w >> 3))) << 7;
    bn = (((s << 3) | (w & 7))) << 7;
  } else {
    const int bps = nwg / SPLITS;     // blocks per split
    split = swz / bps;
    const int rem = swz % bps;
    const int nbn = Nc >> 7;
    bm = (rem / nbn) << 7;
    bn = (rem % nbn) << 7;
  }
  const int klen  = K / SPLITS;
  const int kbase = split * klen;

  const int off0 = (wave << 10) + (lane << 4);
  const int r0   = off0 >> 6;
  const int k0e  = (off0 & 63) >> 1;
  const int r1   = r0 + 64;

  const unsigned short* Ag0 = A + (size_t)(bm + r0) * K + kbase + k0e;
  const unsigned short* Ag1 = A + (size_t)(bm + r1) * K + kbase + k0e;
  const unsigned short* Bg0 = B + (size_t)(bn + r0) * K + kbase + k0e;
  const unsigned short* Bg1 = B + (size_t)(bn + r1) * K + kbase + k0e;

  f32x4 acc[4][4];
#pragma unroll
  for (int m = 0; m < 4; ++m)
#pragma unroll
    for (int n = 0; n < 4; ++n)
      acc[m][n] = (f32x4){0.f, 0.f, 0.f, 0.f};

  const int ldsoff = (wave << 10);

  auto stage = [&](int buf, int kk) {
    char* la = (char*)&As[buf][0] + ldsoff;
    char* lb = (char*)&Bs[buf][0] + ldsoff;
    async16(la,        Ag0 + kk);
    async16(la + 4096, Ag1 + kk);
    async16(lb,        Bg0 + kk);
    async16(lb + 4096, Bg1 + kk);
  };

  stage(0, 0);
  __syncthreads();

  const int nk   = klen >> 5;
  const int arow = (wr << 6) + (lane & 15);
  const int brow = (wc << 6) + (lane & 15);
  const int koff = (lane >> 4) << 3;

  for (int kt = 0; kt < nk; ++kt) {
    const int cur = kt & 1;
    if (kt + 1 < nk) stage(cur ^ 1, (kt + 1) << 5);

    bfx8 af[4], bf[4];
#pragma unroll
    for (int m = 0; m < 4; ++m)
      af[m] = *reinterpret_cast<const bfx8*>(&As[cur][(arow + (m << 4)) * 32 + koff]);
#pragma unroll
    for (int n = 0; n < 4; ++n)
      bf[n] = *reinterpret_cast<const bfx8*>(&Bs[cur][(brow + (n << 4)) * 32 + koff]);

#pragma unroll
    for (int m = 0; m < 4; ++m)
#pragma unroll
      for (int n = 0; n < 4; ++n)
        acc[m][n] = __builtin_amdgcn_mfma_f32_16x16x32_bf16(af[m], bf[n], acc[m][n], 0, 0, 0);

    __syncthreads();  // drains vmcnt: next buffer staged; also guards buffer reuse
  }

  // C/D layout: col = lane&15, row = (lane>>4)*4 + reg
#pragma unroll
  for (int m = 0; m < 4; ++m) {
    const int rowb = bm + (wr << 6) + (m << 4) + ((lane >> 4) << 2);
#pragma unroll
    for (int j = 0; j < 4; ++j) {
      const int r = rowb + j;
      if (MODE == 1) {
        unsigned short* Cb = (unsigned short*)C;
#pragma unroll
        for (int n = 0; n < 4; ++n)
          __builtin_nontemporal_store(f2b(acc[m][n][j]),
              &Cb[(size_t)r * Nc + bn + (wc << 6) + (n << 4) + (lane & 15)]);
        if (ICN) {
          // row r sum of squares over this lane's 4 cols, then the 16-lane group
          float s2 = acc[m][0][j] * acc[m][0][j] + acc[m][1][j] * acc[m][1][j]
                   + acc[m][2][j] * acc[m][2][j] + acc[m][3][j] * acc[m][3][j];
          s2 += __shfl_xor(s2, 1); s2 += __shfl_xor(s2, 2);
          s2 += __shfl_xor(s2, 4); s2 += __shfl_xor(s2, 8);
          if ((lane & 15) == 0) atomicAdd(aux + r, s2);
        }
      } else if (MODE == 0) {
        const float s = 1.0f / aux[r];   // raw rowsums; IEEE divide == old invert_vec
        float* Cf = (float*)C;
#pragma unroll
        for (int n = 0; n < 4; ++n)
          __builtin_nontemporal_store(acc[m][n][j] * s,
              &Cf[(size_t)r * Nc + bn + (wc << 6) + (n << 4) + (lane & 15)]);
      } else {
        unsigned short* Cb = (unsigned short*)C + (size_t)split * M * Nc;
#pragma unroll
        for (int n = 0; n < 4; ++n)
          Cb[(size_t)r * Nc + bn + (wc << 6) + (n << 4) + (lane & 15)] = f2b(acc[m][n][j]);
      }
    }
  }
}

// p[i,j] = adj[i,j] ? exp(lrelu(hT[j,i]*a1[i]*icn[j] + hT[i,j]*a2[j]*icn[i])) : 0
// Vectorized: 8 j per thread. Also accumulates row sums of p into rs_raw[i].
// adj is loaded NON-TEMPORAL (clang ext_vector i32x4): 256MiB read-once stream.
__global__ __launch_bounds__(256)
void scores_kernel(const unsigned short* __restrict__ hT,
                   const int* __restrict__ adj,
                   const float* __restrict__ a,
                   const float* __restrict__ icn,
                   unsigned short* __restrict__ p,
                   float* __restrict__ rs_raw,
                   int strip)
{
  __shared__ unsigned short T1t[64][72];

  const int tid   = threadIdx.x;
  const int i0    = blockIdx.x << 6;
  const int jbase = blockIdx.y * strip;
  const int ntile = strip >> 6;

  const int slot = tid & 7;
  const int jb   = slot << 3;
  const int il0  = tid >> 3;
  const int i_p0 = i0 + il0;
  const int i_p1 = i_p0 + 32;
  const float a1_0 = a[i_p0], ici_0 = icn[i_p0];
  const float a1_1 = a[i_p1], ici_1 = icn[i_p1];
  float rs0 = 0.f, rs1 = 0.f;

  const int rblk0 = (((jb >> 3) ^ ((il0 >> 3) & 7)) << 3);
  const int rblk1 = (((jb >> 3) ^ (((il0 + 32) >> 3) & 7)) << 3);

  for (int jt = 0; jt < ntile; ++jt) {
    const int j0 = jbase + (jt << 6);
    __syncthreads();
#pragma unroll
    for (int ss = 0; ss < 2; ++ss) {
      const int u  = tid + (ss << 8);
      const int jr = u >> 3;
      const int cb = (u & 7) << 3;
      const bfx8 v = *reinterpret_cast<const bfx8*>(hT + (size_t)(j0 + jr) * NN + i0 + cb);
      const int colp = ((((jr >> 3) ^ (u & 7)) << 3) | (jr & 7));
#pragma unroll
      for (int k = 0; k < 8; ++k) T1t[cb + k][colp] = (unsigned short)v[k];
    }
    __syncthreads();

    const int j = j0 + jb;
    const float4 ic0 = *reinterpret_cast<const float4*>(icn + j);
    const float4 ic1 = *reinterpret_cast<const float4*>(icn + j + 4);
    const float4 a20 = *reinterpret_cast<const float4*>(a + NN + j);
    const float4 a21 = *reinterpret_cast<const float4*>(a + NN + j + 4);
    const float icj[8] = {ic0.x, ic0.y, ic0.z, ic0.w, ic1.x, ic1.y, ic1.z, ic1.w};
    const float a2j[8] = {a20.x, a20.y, a20.z, a20.w, a21.x, a21.y, a21.z, a21.w};

#pragma unroll
    for (int ps = 0; ps < 2; ++ps) {
      const int il   = (ps == 0) ? il0 : il0 + 32;
      const int i    = (ps == 0) ? i_p0 : i_p1;
      const float a1 = (ps == 0) ? a1_0 : a1_1;
      const float ii = (ps == 0) ? ici_0 : ici_1;
      const int rb   = (ps == 0) ? rblk0 : rblk1;

      const bfx8 hijv = *reinterpret_cast<const bfx8*>(&T1t[il][rb]);
      const bfx8 hjiv = *reinterpret_cast<const bfx8*>(hT + (size_t)i * NN + j);
      const i32x4 ad0 = __builtin_nontemporal_load(
          reinterpret_cast<const i32x4*>(adj + (size_t)i * NN + j));
      const i32x4 ad1 = __builtin_nontemporal_load(
          reinterpret_cast<const i32x4*>(adj + (size_t)i * NN + j + 4));
      const int adv[8] = {ad0.x, ad0.y, ad0.z, ad0.w, ad1.x, ad1.y, ad1.z, ad1.w};

      bfx8 o;
      float rs = 0.f;
#pragma unroll
      for (int k = 0; k < 8; ++k) {
        const float hij = b2f((unsigned short)hijv[k]);
        const float hji = b2f((unsigned short)hjiv[k]);
        const float e0  = hij * (a1 * icj[k]) + hji * (a2j[k] * ii);
        const float e   = e0 > 0.f ? e0 : 0.2f * e0;
        const float pv  = (adv[k] > 0) ? __expf(e) : 0.f;
        const unsigned short ub = f2b(pv);
        o[k] = (short)ub;
        rs += b2f(ub);   // accumulate the rounded value (matches reading back bf16 p)
      }
      *reinterpret_cast<bfx8*>(p + (size_t)i * NN + j) = o;
      if (ps == 0) rs0 += rs; else rs1 += rs;
    }
  }

  // reduce across the 8 j-slot lanes (lane groups are 8-aligned)
#pragma unroll
  for (int o = 1; o < 8; o <<= 1) {
    rs0 += __shfl_xor(rs0, o);
    rs1 += __shfl_xor(rs1, o);
  }
  if (slot == 0) {
    atomicAdd(rs_raw + i_p0, rs0);
    atomicAdd(rs_raw + i_p1, rs1);
  }
}

extern "C" void kernel_launch(void* const* d_in, const int* in_sizes, int n_in,
                              void* d_out, int out_size, void* d_ws, size_t ws_size,
                              hipStream_t stream)
{
  (void)in_sizes; (void)n_in; (void)out_size; (void)ws_size;
  const float* x   = (const float*)d_in[0];
  const int*   adj = (const int*)d_in[1];
  const float* W   = (const float*)d_in[2];
  const float* a   = (const float*)d_in[3];
  float* out = (float*)d_out;

  char* ws = (char*)d_ws;
  // layout (no recycling; ~288 MiB used, ws ~1 GiB per poison fill):
  //   hT 128MiB | p 128MiB | icn 32KiB | irs 32KiB | xb 8MiB | Wb 8MiB | xT 8MiB | Axb 8MiB
  // split-K bf16 partials (8 x 8MiB) live in d_out, dead before gemm2b writes it.
  unsigned short* hT = (unsigned short*)ws;
  unsigned short* p  = (unsigned short*)(ws + 134217728ull);
  float* icn = (float*)(ws + 268435456ull);
  float* irs = (float*)(ws + 268435456ull + 32768ull);
  unsigned short* xb  = (unsigned short*)(ws + 268435456ull + 65536ull);
  unsigned short* Wb  = xb + (size_t)NN * KIN;
  unsigned short* xT  = Wb + (size_t)NN * KIN;
  unsigned short* Axb = xT + (size_t)NN * KIN;
  unsigned short* parts = (unsigned short*)out;   // 64MiB bf16, overwritten later

  // zero icn_raw (gemm1's fused col-norm accumulator) + irs_raw (scores' rowsums)
  hipMemsetAsync(icn, 0, 65536, stream);

  // xb + xT from a single read of x; W -> Wb in the same launch
  transpose_cvt<<<dim3(NN / 64, KIN / 64), 256, 0, stream>>>(x, xT, xb, W, Wb, NN, KIN);

  // hT[j,i] = sum_k W[j,k] x[i,k]; fused: icn_raw[j] += sum_i h[j,i]^2 (fp32 acc)
  gemm_bt<1, 1, 1, 1><<<4096, 256, 0, stream>>>(Wb, xb, hT, icn, NN, NN, KIN);

  // icn[j] = 1 / sqrt(icn_raw[j])
  final_rsq<<<NN / 256, 256, 0, stream>>>(icn);

  // p[i,j] = adj ? exp(lrelu(...)) : 0 ; raw rowsums -> irs. NT adj loads.
  scores_kernel<<<dim3(128, 32), 256, 0, stream>>>(hT, adj, a, icn, p, irs, NN / 32);

  // Ax[i,c] = sum_j p[i,j] * x[j,c]  (split-K 8, bf16 partials in d_out)
  gemm_bt<2, 8, 0, 0><<<2048, 256, 0, stream>>>(p, xT, parts, nullptr, NN, KIN, NN);

  // Axb = bf16(sum of 8 bf16 partial planes)
  reduce_cvt<<<NN * KIN / 8 / 256, 256, 0, stream>>>(parts, Axb, NN * KIN / 8);

  // out[i,j] = (sum_c Ax[i,c] * W[j,c]) / rowsum[i]  (K=512; 1/x folded in)
  gemm_bt<0, 1, 1, 0><<<4096, 256, 0, stream>>>(Axb, Wb, out, irs, NN, NN, KIN);
}